// Round 2
// baseline (167.807 us; speedup 1.0000x reference)
//
#include <hip/hip_runtime.h>

// Bit-serial SAR ADC quantizer.
// Outputs concatenated in d_out: q [8192*1024] f32, Q [8192*1024*8] f32 (bit innermost), W [36] f32.
//
// R1: Q-stores were 16B/lane at 128B lane-stride (8x store transactions).
//     Now staged through XOR-swizzled LDS and written back fully coalesced.

constexpr int NB     = 8;
constexpr int TOTAL  = 8192 * 1024;        // LENGTH * PACKET
constexpr int Q_OFF  = TOTAL;              // start of Q region (elements)
constexpr int W_OFF  = TOTAL * (NB + 1);   // start of W region (elements)
constexpr float VRC  = 1.0f / 256.0f;      // VR (exact power of two)
constexpr int ELEMS_PER_BLOCK = 1024;      // 256 threads x 4 elements
constexpr int NBLOCKS = TOTAL / ELEMS_PER_BLOCK;  // 8192

__global__ __launch_bounds__(256) void sar_adc_kernel(
    const float* __restrict__ x,
    const float* __restrict__ W,
    float* __restrict__ out)
{
    __shared__ float4 lds[2048];   // 32 KiB: 256 threads x 8 float4

    // W uniform; constant indices -> s_loads/SGPRs.
    float w[36];
#pragma unroll
    for (int i = 0; i < 36; ++i) w[i] = W[i];

    if (blockIdx.x == 0 && threadIdx.x < 36) {
        out[W_OFF + threadIdx.x] = w[threadIdx.x];
    }

    const float4* __restrict__ x4 = (const float4*)x;
    float4* __restrict__ q4 = (float4*)out;
    float4* __restrict__ Q4 = (float4*)(out + Q_OFF);

    const int t    = threadIdx.x;
    const int tile = blockIdx.x;             // one 1024-element tile per block
    const int vin  = tile * 256 + t;         // float4 index into x / q

    const float4 xv = x4[vin];               // coalesced 16B/lane
    const float xe[4] = {xv.x, xv.y, xv.z, xv.w};
    float qout[4];
    float Qb[4][NB];

#pragma unroll
    for (int e = 0; e < 4; ++e) {
        // Work in the x/VR domain: all VR scalings are exact powers of two,
        // so sign decisions are bit-identical to the reference.
        const float xs = xe[e] * 256.0f;
        bool bit[NB];
        int m = 35;
#pragma unroll
        for (int j = NB - 1; j >= 0; --j) {
            float bs = w[m]; m--;            // W[m] * VREF (scaled out)
#pragma unroll
            for (int k = j + 1; k < NB; ++k) {
                // (Qk+1)/2 in {0,1}: select + add, reference accumulation order,
                // no multiply -> no FMA contraction rounding hazard.
                bs += bit[k] ? w[m] : 0.0f;
                m--;
            }
            // sign(diff + 1e-30): diff==0 -> +1; else sign(diff).
            bit[j] = (xs - bs) >= 0.0f;
        }
        int n = 0;
#pragma unroll
        for (int b = 0; b < NB; ++b) {
            Qb[e][b] = bit[b] ? 1.0f : -1.0f;
            n += bit[b] ? (1 << b) : 0;
        }
        qout[e] = (float)n * VRC;            // exact: n <= 255
    }

    q4[vin] = make_float4(qout[0], qout[1], qout[2], qout[3]);   // coalesced

    // Stage this thread's 8 float4 of Q into LDS, XOR-swizzled so bank groups
    // rotate across lanes on both the write and the read side.
#pragma unroll
    for (int i = 0; i < 8; ++i) {
        const int e  = i >> 1;
        const int b0 = (i & 1) * 4;
        lds[t * 8 + (i ^ (t & 7))] =
            make_float4(Qb[e][b0 + 0], Qb[e][b0 + 1], Qb[e][b0 + 2], Qb[e][b0 + 3]);
    }

    __syncthreads();

    // Coalesced write-back: store s, lane t -> contiguous float4 s*256 + t.
    const int qbase = tile * 2048;           // float4 index into Q region
#pragma unroll
    for (int s = 0; s < 8; ++s) {
        const int f   = s * 256 + t;         // compute-order slot within block
        const int tw  = f >> 3;              // thread that produced it
        const int iw  = f & 7;               // its chunk index
        Q4[qbase + f] = lds[tw * 8 + (iw ^ (tw & 7))];
    }
}

extern "C" void kernel_launch(void* const* d_in, const int* in_sizes, int n_in,
                              void* d_out, int out_size, void* d_ws, size_t ws_size,
                              hipStream_t stream) {
    const float* x = (const float*)d_in[0];
    const float* W = (const float*)d_in[1];
    float* out = (float*)d_out;

    sar_adc_kernel<<<NBLOCKS, 256, 0, stream>>>(x, W, out);
}

// Round 4
// 155.199 us; speedup vs baseline: 1.0812x; 1.0812x over previous
//
#include <hip/hip_runtime.h>

// Bit-serial SAR ADC quantizer.
// Outputs concatenated in d_out: q [8192*1024] f32, Q [8192*1024*8] f32 (bit innermost), W [36] f32.
//
// R1: LDS-coalesced Q stores (neutral vs R0 -> pattern wasn't the lever).
// R2: counters showed 2.0x WRITE amplification + 77 MiB extra FETCH (L2/MALL
//     allocate churn on write-once data). All output stores + x load are now
//     NONTEMPORAL; LDS coalescing kept so each nt store instruction covers
//     full cache lines (1024 B contiguous per wave).
// R3: __builtin_nontemporal_* requires a native clang vector type, not
//     HIP_vector_type -> use ext_vector_type(4) float.

typedef float f4 __attribute__((ext_vector_type(4)));

constexpr int NB     = 8;
constexpr int TOTAL  = 8192 * 1024;        // LENGTH * PACKET
constexpr int Q_OFF  = TOTAL;              // start of Q region (elements)
constexpr int W_OFF  = TOTAL * (NB + 1);   // start of W region (elements)
constexpr float VRC  = 1.0f / 256.0f;      // VR (exact power of two)
constexpr int NBLOCKS = TOTAL / 1024;      // 8192 blocks, 1024 elems each

__global__ __launch_bounds__(256) void sar_adc_kernel(
    const float* __restrict__ x,
    const float* __restrict__ W,
    float* __restrict__ out)
{
    __shared__ f4 lds[2048];   // 32 KiB: 256 threads x 8 float4

    // W uniform; constant indices -> s_loads/SGPRs.
    float w[36];
#pragma unroll
    for (int i = 0; i < 36; ++i) w[i] = W[i];

    if (blockIdx.x == 0 && threadIdx.x < 36) {
        out[W_OFF + threadIdx.x] = w[threadIdx.x];
    }

    const f4* __restrict__ x4 = (const f4*)x;
    f4* __restrict__ q4 = (f4*)out;
    f4* __restrict__ Q4 = (f4*)(out + Q_OFF);

    const int t    = threadIdx.x;
    const int tile = blockIdx.x;             // one 1024-element tile per block
    const int vin  = tile * 256 + t;         // float4 index into x / q

    const f4 xv = __builtin_nontemporal_load(&x4[vin]);  // read-once
    const float xe[4] = {xv.x, xv.y, xv.z, xv.w};
    float qout[4];
    float Qb[4][NB];

#pragma unroll
    for (int e = 0; e < 4; ++e) {
        // Work in the x/VR domain: all VR scalings are exact powers of two,
        // so sign decisions are bit-identical to the reference.
        const float xs = xe[e] * 256.0f;
        bool bit[NB];
        int m = 35;
#pragma unroll
        for (int j = NB - 1; j >= 0; --j) {
            float bs = w[m]; m--;            // W[m] * VREF (scaled out)
#pragma unroll
            for (int k = j + 1; k < NB; ++k) {
                // (Qk+1)/2 in {0,1}: select + add, reference accumulation order,
                // no multiply -> no FMA contraction rounding hazard.
                bs += bit[k] ? w[m] : 0.0f;
                m--;
            }
            // sign(diff + 1e-30): diff==0 -> +1; else sign(diff).
            bit[j] = (xs - bs) >= 0.0f;
        }
        int n = 0;
#pragma unroll
        for (int b = 0; b < NB; ++b) {
            Qb[e][b] = bit[b] ? 1.0f : -1.0f;
            n += bit[b] ? (1 << b) : 0;
        }
        qout[e] = (float)n * VRC;            // exact: n <= 255
    }

    {
        f4 qv = {qout[0], qout[1], qout[2], qout[3]};
        __builtin_nontemporal_store(qv, &q4[vin]);   // coalesced, streaming
    }

    // Stage this thread's 8 float4 of Q into LDS, XOR-swizzled so bank groups
    // rotate across lanes on both the write and the read side.
#pragma unroll
    for (int i = 0; i < 8; ++i) {
        const int e  = i >> 1;
        const int b0 = (i & 1) * 4;
        f4 qb = {Qb[e][b0 + 0], Qb[e][b0 + 1], Qb[e][b0 + 2], Qb[e][b0 + 3]};
        lds[t * 8 + (i ^ (t & 7))] = qb;
    }

    __syncthreads();

    // Coalesced streaming write-back: store s, lane t -> contiguous float4.
    const int qbase = tile * 2048;           // float4 index into Q region
#pragma unroll
    for (int s = 0; s < 8; ++s) {
        const int f   = s * 256 + t;         // compute-order slot within block
        const int tw  = f >> 3;              // thread that produced it
        const int iw  = f & 7;               // its chunk index
        __builtin_nontemporal_store(lds[tw * 8 + (iw ^ (tw & 7))], &Q4[qbase + f]);
    }
}

extern "C" void kernel_launch(void* const* d_in, const int* in_sizes, int n_in,
                              void* d_out, int out_size, void* d_ws, size_t ws_size,
                              hipStream_t stream) {
    const float* x = (const float*)d_in[0];
    const float* W = (const float*)d_in[1];
    float* out = (float*)d_out;

    sar_adc_kernel<<<NBLOCKS, 256, 0, stream>>>(x, W, out);
}